// Round 12
// baseline (202.946 us; speedup 1.0000x reference)
//
#include <hip/hip_runtime.h>
#include <hip/hip_bf16.h>

#define BATCH   2
#define SEQ     512
#define DMODEL  1024
#define DSTATE  64
#define HEADDIM 64
#define DCONV   4
#define VNUM    3
#define HORIZON 20
#define DINNER  2048
#define NHEADS  32
#define CONVDIM 2176   // DINNER + 2*DSTATE
#define DINPROJ 4256   // 2*DINNER + 2*DSTATE + NHEADS
#define NPAD1   4352   // DINPROJ padded to 128
#define BS      (BATCH*SEQ)   // 1024
#define RMS_EPS 1e-5f
#define CHUNK   64
#define NCHUNK  (SEQ/CHUNK)   // 8
#define NDEC    (VNUM + HORIZON*VNUM)   // 63 decoder rows
#define WC_DS   32                      // split-K slices for weight fold
#define LDB     72                      // bf16 LDS row stride (144B, 16-aligned)

typedef __attribute__((ext_vector_type(8))) short bf16x8;
typedef __attribute__((ext_vector_type(4))) float f32x4;

__device__ __forceinline__ unsigned short f2b(float x) {
    union { float f; unsigned u; } v; v.f = x;
    return (unsigned short)((v.u + 0x7fffu + ((v.u >> 16) & 1u)) >> 16);  // RNE
}

__device__ __forceinline__ float silu(float x) { return x / (1.f + expf(-x)); }

__device__ __forceinline__ void async16(const void* g, const void* l) {
    __builtin_amdgcn_global_load_lds(
        (const __attribute__((address_space(1))) unsigned int*)g,
        (__attribute__((address_space(3))) unsigned int*)l, 16, 0, 0);
}

// ---------------------------------------------------------------------------
// bf16 MFMA GEMM (NT): C[M,N]fp32 = A[M,KD]bf16 * B[Npad,KD]bf16^T.
// ---------------------------------------------------------------------------
template<int BM, int BN, int FM, int FN, int KD>
__global__ __launch_bounds__(256) void gemm_bf16(const short* __restrict__ A,
                                                 const short* __restrict__ B,
                                                 float* __restrict__ C, int N) {
    constexpr int WM = FM * 16, WN = FN * 16;
    static_assert(BM == 2 * WM && BN == 2 * WN, "2x2 waves");
    __shared__ __align__(16) short At[BM * 32];
    __shared__ __align__(16) short Bt[BN * 32];
    const int t    = threadIdx.x;
    const int lane = t & 63;
    const int w    = t >> 6;
    const int wm   = (w >> 1) * WM, wn = (w & 1) * WN;
    const int row0 = blockIdx.y * BM, col0 = blockIdx.x * BN;
    const int fr   = lane & 15;
    const int kq   = lane >> 4;
    const int lr   = t >> 2;
    const int lc   = (t & 3) * 8;

    const short* Ag = A + (size_t)(row0 + lr) * KD + lc;
    const short* Bg = B + (size_t)(col0 + lr) * KD + lc;

    f32x4 acc[FM][FN];
#pragma unroll
    for (int i = 0; i < FM; ++i)
#pragma unroll
        for (int j = 0; j < FN; ++j)
#pragma unroll
            for (int r = 0; r < 4; ++r) acc[i][j][r] = 0.f;

    for (int k0 = 0; k0 < KD; k0 += 32) {
        __syncthreads();
#pragma unroll
        for (int i = 0; i < BM / 64; ++i)
            async16(Ag + (size_t)i * 64 * KD + k0, (const char*)At + i * 4096 + t * 16);
#pragma unroll
        for (int i = 0; i < BN / 64; ++i)
            async16(Bg + (size_t)i * 64 * KD + k0, (const char*)Bt + i * 4096 + t * 16);
        __syncthreads();

        bf16x8 af[FM], bv[FN];
#pragma unroll
        for (int i = 0; i < FM; ++i)
            af[i] = *(const bf16x8*)&At[(wm + i * 16 + fr) * 32 + kq * 8];
#pragma unroll
        for (int j = 0; j < FN; ++j)
            bv[j] = *(const bf16x8*)&Bt[(wn + j * 16 + fr) * 32 + kq * 8];
#pragma unroll
        for (int i = 0; i < FM; ++i)
#pragma unroll
            for (int j = 0; j < FN; ++j)
                acc[i][j] = __builtin_amdgcn_mfma_f32_16x16x32_bf16(
                    af[i], bv[j], acc[i][j], 0, 0, 0);
    }

    const int orow = lane >> 4;
#pragma unroll
    for (int i = 0; i < FM; ++i)
#pragma unroll
        for (int j = 0; j < FN; ++j) {
            const int col = col0 + wn + j * 16 + fr;
            if (col < N) {
#pragma unroll
                for (int r = 0; r < 4; ++r) {
                    const int row = row0 + wm + i * 16 + orow * 4 + r;
                    C[(size_t)row * N + col] = acc[i][j][r];
                }
            }
        }
}

// ---------------------------------------------------------------------------
// prep: fused fp32->bf16 casts (embed + padded in_proj_w) AND decoder weight
// fold pass 1.  P[ds][v][i] = sum_{d in 32-slice} decw[v][d] * op[d][i]
// ---------------------------------------------------------------------------
#define EMB4     (BS * DMODEL / 4)          // 262144
#define IPW4     (NPAD1 * DMODEL / 4)       // 1114112
#define CASTBLKS ((EMB4 + IPW4) / 256)      // 5376
__global__ __launch_bounds__(256) void prep_kernel(
        const float* __restrict__ embed, const float* __restrict__ ipw,
        short* __restrict__ embB, short* __restrict__ ipwB,
        const float* __restrict__ op, const float* __restrict__ cwv,
        const float* __restrict__ fwv, float* __restrict__ P) {
    __shared__ float lw[32][64];   // [d][v], v padded to 64 with zeros
    if (blockIdx.x < CASTBLKS) {
        const int i = blockIdx.x * 256 + threadIdx.x;
        if (i < EMB4) {
            float4 v = *(const float4*)(embed + (size_t)i * 4);
            *(short4*)(embB + (size_t)i * 4) =
                make_short4((short)f2b(v.x), (short)f2b(v.y),
                            (short)f2b(v.z), (short)f2b(v.w));
        } else {
            const int j = i - EMB4;
            const size_t e0 = (size_t)j * 4;
            const int row = (int)(e0 / DMODEL);
            short4 o;
            if (row < DINPROJ) {
                float4 v = *(const float4*)(ipw + e0);
                o = make_short4((short)f2b(v.x), (short)f2b(v.y),
                                (short)f2b(v.z), (short)f2b(v.w));
            } else {
                o = make_short4(0, 0, 0, 0);
            }
            *(short4*)(ipwB + e0) = o;
        }
        return;
    }
    const int blk   = blockIdx.x - CASTBLKS;   // 0..255
    const int itile = blk & 7;
    const int ds    = blk >> 3;
    const int i     = itile * 256 + threadIdx.x;
    const int d0    = ds * 32;

#pragma unroll
    for (int k = 0; k < 8; ++k) {
        const int e = threadIdx.x * 8 + k;    // 0..2047
        const int d = e >> 6, v = e & 63;
        float val = 0.f;
        if (v < VNUM)      val = cwv[(size_t)v * DMODEL + d0 + d];
        else if (v < NDEC) val = fwv[(size_t)(v - VNUM) * DMODEL + d0 + d];
        lw[d][v] = val;
    }

    float opc[32];
#pragma unroll
    for (int d = 0; d < 32; ++d) opc[d] = op[(size_t)(d0 + d) * DINNER + i];
    __syncthreads();

    f32x4 acc[16];
#pragma unroll
    for (int q = 0; q < 16; ++q)
#pragma unroll
        for (int r = 0; r < 4; ++r) acc[q][r] = 0.f;

#pragma unroll
    for (int d = 0; d < 32; ++d) {
        const float o = opc[d];
#pragma unroll
        for (int q = 0; q < 16; ++q) {
            float4 wv = *(const float4*)&lw[d][q * 4];
            acc[q][0] += o * wv.x; acc[q][1] += o * wv.y;
            acc[q][2] += o * wv.z; acc[q][3] += o * wv.w;
        }
    }

    float* Pp = P + (size_t)ds * 64 * DINNER + i;
#pragma unroll
    for (int q = 0; q < 16; ++q)
#pragma unroll
        for (int r = 0; r < 4; ++r)
            Pp[(size_t)(q * 4 + r) * DINNER] = acc[q][r];
}

// ---------------------------------------------------------------------------
// Causal conv1d(4)+bias+SiLU over the xBC slice, vectorized x4, coalesced.
// ---------------------------------------------------------------------------
#define CONVBLKS (BS * CONVDIM / 4 / 256)   // 2176
__global__ __launch_bounds__(256) void conv_kernel(
        const float* __restrict__ zxbcdt, const float* __restrict__ cw,
        const float* __restrict__ cb, float* __restrict__ xbc) {
    const int item = blockIdx.x * 256 + threadIdx.x;
    const int c4 = item % (CONVDIM / 4);
    const int rs = item / (CONVDIM / 4);
    const int s  = rs % SEQ;
    const int c  = c4 * 4;
    const float* src = zxbcdt + (size_t)rs * DINPROJ + DINNER + c;
    float4 x0 = (s >= 3) ? *(const float4*)(src - 3 * DINPROJ) : make_float4(0,0,0,0);
    float4 x1 = (s >= 2) ? *(const float4*)(src - 2 * DINPROJ) : make_float4(0,0,0,0);
    float4 x2 = (s >= 1) ? *(const float4*)(src - 1 * DINPROJ) : make_float4(0,0,0,0);
    float4 x3 = *(const float4*)(src);
    float4 bias = *(const float4*)(cb + c);
    float4 r;
    { float4 w = *(const float4*)(cw + (size_t)(c+0)*4);
      r.x = bias.x + w.x*x0.x + w.y*x1.x + w.z*x2.x + w.w*x3.x; }
    { float4 w = *(const float4*)(cw + (size_t)(c+1)*4);
      r.y = bias.y + w.x*x0.y + w.y*x1.y + w.z*x2.y + w.w*x3.y; }
    { float4 w = *(const float4*)(cw + (size_t)(c+2)*4);
      r.z = bias.z + w.x*x0.z + w.y*x1.z + w.z*x2.z + w.w*x3.z; }
    { float4 w = *(const float4*)(cw + (size_t)(c+3)*4);
      r.w = bias.w + w.x*x0.w + w.y*x1.w + w.z*x2.w + w.w*x3.w; }
    r.x = silu(r.x); r.y = silu(r.y); r.z = silu(r.z); r.w = silu(r.w);
    *(float4*)(xbc + (size_t)rs * CONVDIM + c) = r;
}

// ---------------------------------------------------------------------------
// Chunked SSD scan, pass A — MFMA (R9-proven version: upfront staging,
// 6 LDS arrays, no atomics).
// ---------------------------------------------------------------------------
__global__ __launch_bounds__(256) void chunk_intra_kernel(
        const float* __restrict__ zx, const float* __restrict__ xbc,
        const float* __restrict__ dt_bias, const float* __restrict__ A_log,
        const float* __restrict__ Dv, float* __restrict__ yraw,
        float* __restrict__ Sc, float* __restrict__ dexp) {
    const int blk = blockIdx.x;      // ((b*32+h)*8 + c)
    const int c  = blk & 7;
    const int bh = blk >> 3;
    const int h  = bh & 31;
    const int b  = bh >> 5;
    const int rs0 = b * SEQ + c * CHUNK;

    __shared__ __align__(16) short sB [64 * LDB];  // [s][n]
    __shared__ __align__(16) short sCt[64 * LDB];  // [t][n]
    __shared__ __align__(16) short sBn[64 * LDB];  // [n][s]
    __shared__ __align__(16) short sUt[64 * LDB];  // [p][s]
    __shared__ __align__(16) short sUe[64 * LDB];  // [p][s] * se[s]
    __shared__ __align__(16) short sM [64 * LDB];  // [t][s]
    __shared__ float sl[64], se[64], sdt[64];

    const int tid  = threadIdx.x;
    const int lane = tid & 63;
    const int w    = tid >> 6;
    const int fr   = lane & 15;
    const int kq   = lane >> 4;
    const int wm   = w * 16;       // wave's 16-row output strip
    const float A  = -expf(A_log[h]);

    // ---- stage B[s][n], C[t][n] (row-major) and Bn[n][s] (transposed) ----
    {
        const int row = tid >> 2;
        const int cq  = tid & 3;
        const float* xrow = xbc + (size_t)(rs0 + row) * CONVDIM + DINNER;
#pragma unroll
        for (int i = 0; i < 4; ++i) {
            const int n = cq * 16 + i * 4;
            float4 bv = *(const float4*)(xrow + n);
            float4 cv = *(const float4*)(xrow + DSTATE + n);
            short4 bs = make_short4((short)f2b(bv.x), (short)f2b(bv.y),
                                    (short)f2b(bv.z), (short)f2b(bv.w));
            short4 cs = make_short4((short)f2b(cv.x), (short)f2b(cv.y),
                                    (short)f2b(cv.z), (short)f2b(cv.w));
            *(short4*)&sB [row * LDB + n] = bs;
            *(short4*)&sCt[row * LDB + n] = cs;
            sBn[(n+0) * LDB + row] = bs.x;
            sBn[(n+1) * LDB + row] = bs.y;
            sBn[(n+2) * LDB + row] = bs.z;
            sBn[(n+3) * LDB + row] = bs.w;
        }
    }

    // ---- dt = softplus(raw + bias); cumsum(dt*A) (wave 0) ----
    if (tid < 64) {
        const float raw = zx[(size_t)(rs0 + tid) * DINPROJ + DINNER + CONVDIM + h]
                          + dt_bias[h];
        const float dtv = fmaxf(raw, 0.f) + log1pf(expf(-fabsf(raw)));
        sdt[tid] = dtv;
        float v = dtv * A;
#pragma unroll
        for (int off = 1; off < 64; off <<= 1) {
            float o = __shfl_up(v, off, 64);
            if (tid >= off) v += o;
        }
        sl[tid] = v;
        const float ltot = __shfl(v, 63, 64);
        se[tid] = expf(ltot - v);
        dexp[(size_t)blk * 64 + tid] = expf(v);
    }
    __syncthreads();

    // ---- GEMM1: Mraw (strip t in [wm, wm+16)) ----
    f32x4 accM[4];
#pragma unroll
    for (int j = 0; j < 4; ++j)
#pragma unroll
        for (int r = 0; r < 4; ++r) accM[j][r] = 0.f;
#pragma unroll
    for (int k0 = 0; k0 < 64; k0 += 32) {
        bf16x8 af = *(const bf16x8*)&sCt[(wm + fr) * LDB + kq * 8 + k0];
#pragma unroll
        for (int j = 0; j < 4; ++j) {
            bf16x8 bv = *(const bf16x8*)&sB[(j * 16 + fr) * LDB + kq * 8 + k0];
            accM[j] = __builtin_amdgcn_mfma_f32_16x16x32_bf16(af, bv, accM[j], 0, 0, 0);
        }
    }
    // mask + exp, write M[t][s] bf16
    {
        const int t0 = wm + kq * 4;
        const float lt0 = sl[t0+0], lt1 = sl[t0+1], lt2 = sl[t0+2], lt3 = sl[t0+3];
#pragma unroll
        for (int j = 0; j < 4; ++j) {
            const int s = j * 16 + fr;
            const float ls = sl[s];
            sM[(t0+0)*LDB + s] = (short)f2b((s <= t0+0) ? expf(lt0-ls)*accM[j][0] : 0.f);
            sM[(t0+1)*LDB + s] = (short)f2b((s <= t0+1) ? expf(lt1-ls)*accM[j][1] : 0.f);
            sM[(t0+2)*LDB + s] = (short)f2b((s <= t0+2) ? expf(lt2-ls)*accM[j][2] : 0.f);
            sM[(t0+3)*LDB + s] = (short)f2b((s <= t0+3) ? expf(lt3-ls)*accM[j][3] : 0.f);
        }
    }

    // ---- stage Ut[p][s] = dt_s*x[s][p] and Ue = Ut*se[s] ----
    {
        const int row = tid >> 2;     // s
        const int cq  = tid & 3;
        const float dtv = sdt[row];
        const float sev = se[row];
        const float* xr = xbc + (size_t)(rs0 + row) * CONVDIM + h * HEADDIM;
#pragma unroll
        for (int i = 0; i < 4; ++i) {
            const int p = cq * 16 + i * 4;
            float4 xv = *(const float4*)(xr + p);
            const float u0 = dtv * xv.x, u1 = dtv * xv.y;
            const float u2 = dtv * xv.z, u3 = dtv * xv.w;
            sUt[(p+0)*LDB + row] = (short)f2b(u0);
            sUt[(p+1)*LDB + row] = (short)f2b(u1);
            sUt[(p+2)*LDB + row] = (short)f2b(u2);
            sUt[(p+3)*LDB + row] = (short)f2b(u3);
            sUe[(p+0)*LDB + row] = (short)f2b(u0 * sev);
            sUe[(p+1)*LDB + row] = (short)f2b(u1 * sev);
            sUe[(p+2)*LDB + row] = (short)f2b(u2 * sev);
            sUe[(p+3)*LDB + row] = (short)f2b(u3 * sev);
        }
    }
    __syncthreads();

    // ---- GEMM2: Y (strip t = wm) ----
    f32x4 accY[4];
#pragma unroll
    for (int j = 0; j < 4; ++j)
#pragma unroll
        for (int r = 0; r < 4; ++r) accY[j][r] = 0.f;
#pragma unroll
    for (int k0 = 0; k0 < 64; k0 += 32) {
        bf16x8 af = *(const bf16x8*)&sM[(wm + fr) * LDB + kq * 8 + k0];
#pragma unroll
        for (int j = 0; j < 4; ++j) {
            bf16x8 bv = *(const bf16x8*)&sUt[(j * 16 + fr) * LDB + kq * 8 + k0];
            accY[j] = __builtin_amdgcn_mfma_f32_16x16x32_bf16(af, bv, accY[j], 0, 0, 0);
        }
    }
    // ---- GEMM3: Sc (strip p = wm) ----
    f32x4 accS[4];
#pragma unroll
    for (int j = 0; j < 4; ++j)
#pragma unroll
        for (int r = 0; r < 4; ++r) accS[j][r] = 0.f;
#pragma unroll
    for (int k0 = 0; k0 < 64; k0 += 32) {
        bf16x8 af = *(const bf16x8*)&sUe[(wm + fr) * LDB + kq * 8 + k0];
#pragma unroll
        for (int j = 0; j < 4; ++j) {
            bf16x8 bv = *(const bf16x8*)&sBn[(j * 16 + fr) * LDB + kq * 8 + k0];
            accS[j] = __builtin_amdgcn_mfma_f32_16x16x32_bf16(af, bv, accS[j], 0, 0, 0);
        }
    }

    // ---- Y epilogue (+ D*x, exact fp32 x) ----
    {
        const float Dh = Dv[h];
        const int t0 = wm + kq * 4;
#pragma unroll
        for (int r = 0; r < 4; ++r) {
            const int t = t0 + r;
            const float* xr = xbc + (size_t)(rs0 + t) * CONVDIM + h * HEADDIM;
            float* yr = yraw + (size_t)(rs0 + t) * DINNER + h * HEADDIM;
#pragma unroll
            for (int j = 0; j < 4; ++j) {
                const int p = j * 16 + fr;
                yr[p] = accY[j][r] + Dh * xr[p];
            }
        }
    }
    // ---- Sc epilogue ----
    {
        float* scp = Sc + (size_t)blk * (HEADDIM * DSTATE);
        const int p0 = wm + kq * 4;
#pragma unroll
        for (int r = 0; r < 4; ++r)
#pragma unroll
            for (int j = 0; j < 4; ++j)
                scp[(size_t)(p0 + r) * DSTATE + j * 16 + fr] = accS[j][r];
    }
}

// ---------------------------------------------------------------------------
// Fused pass B (inter-chunk state combine, 4 blocks per (b,h))
// + decoder weight fold pass 2.
// ---------------------------------------------------------------------------
__global__ __launch_bounds__(256) void comb_reduce_kernel(
        const float* __restrict__ Sc, const float* __restrict__ dexp,
        float* __restrict__ h0ws, const float* __restrict__ P,
        float* __restrict__ W) {
    if (blockIdx.x < 256) {
        const int bh = blockIdx.x >> 2;
        const int e  = (blockIdx.x & 3) * 1024 + threadIdx.x * 4;
        float4 h = make_float4(0.f, 0.f, 0.f, 0.f);
        for (int c = 0; c < NCHUNK; ++c) {
            const size_t base = (size_t)(bh * NCHUNK + c) * (HEADDIM * DSTATE);
            const float ac = dexp[(size_t)(bh * NCHUNK + c) * 64 + 63];
            *(float4*)&h0ws[base + e] = h;
            float4 s = *(const float4*)&Sc[base + e];
            h.x = ac * h.x + s.x; h.y = ac * h.y + s.y;
            h.z = ac * h.z + s.z; h.w = ac * h.w + s.w;
        }
    } else {
        const int idx = (blockIdx.x - 256) * 256 + threadIdx.x;   // < 64*DINNER
        float s = 0.f;
#pragma unroll
        for (int ds = 0; ds < WC_DS; ++ds) s += P[(size_t)ds * 64 * DINNER + idx];
        W[idx] = s;
    }
}

// ---------------------------------------------------------------------------
// Pass C — MFMA: Yst[t][p] = dexp[t] * sum_n C[t][n] h0[p][n].
// ---------------------------------------------------------------------------
__global__ __launch_bounds__(256) void chunk_state_out_kernel(
        const float* __restrict__ xbc, const float* __restrict__ h0ws,
        const float* __restrict__ dexp, float* __restrict__ yraw) {
    const int blk = blockIdx.x;
    const int c  = blk & 7;
    if (c == 0) return;
    const int bh = blk >> 3;
    const int h  = bh & 31;
    const int b  = bh >> 5;
    const int rs0 = b * SEQ + c * CHUNK;

    __shared__ __align__(16) short sCt[64 * LDB];  // [t][n]
    __shared__ __align__(16) short sH [64 * LDB];  // [p][n]
    __shared__ float sdex[64];

    const int tid  = threadIdx.x;
    const int lane = tid & 63;
    const int w    = tid >> 6;
    const int fr   = lane & 15;
    const int kq   = lane >> 4;
    const int wm   = w * 16;
    {
        const int row = tid >> 2;
        const int cq  = tid & 3;
        const float* xrow = xbc + (size_t)(rs0 + row) * CONVDIM + DINNER + DSTATE;
        const float* hrow = h0ws + (size_t)blk * (HEADDIM * DSTATE)
                            + (size_t)row * DSTATE;
#pragma unroll
        for (int i = 0; i < 4; ++i) {
            const int n = cq * 16 + i * 4;
            float4 cv = *(const float4*)(xrow + n);
            float4 hv = *(const float4*)(hrow + n);
            *(short4*)&sCt[row * LDB + n] =
                make_short4((short)f2b(cv.x), (short)f2b(cv.y),
                            (short)f2b(cv.z), (short)f2b(cv.w));
            *(short4*)&sH[row * LDB + n] =
                make_short4((short)f2b(hv.x), (short)f2b(hv.y),
                            (short)f2b(hv.z), (short)f2b(hv.w));
        }
    }
    if (tid < 64) sdex[tid] = dexp[(size_t)blk * 64 + tid];
    __syncthreads();

    f32x4 acc[4];
#pragma unroll
    for (int j = 0; j < 4; ++j)
#pragma unroll
        for (int r = 0; r < 4; ++r) acc[j][r] = 0.f;
#pragma unroll
    for (int k0 = 0; k0 < 64; k0 += 32) {
        bf16x8 af = *(const bf16x8*)&sCt[(wm + fr) * LDB + kq * 8 + k0];
#pragma unroll
        for (int j = 0; j < 4; ++j) {
            bf16x8 bv = *(const bf16x8*)&sH[(j * 16 + fr) * LDB + kq * 8 + k0];
            acc[j] = __builtin_amdgcn_mfma_f32_16x16x32_bf16(af, bv, acc[j], 0, 0, 0);
        }
    }
    const int t0 = wm + kq * 4;
#pragma unroll
    for (int r = 0; r < 4; ++r) {
        const int t = t0 + r;
        const float d = sdex[t];
        float* yr = yraw + (size_t)(rs0 + t) * DINNER + h * HEADDIM;
#pragma unroll
        for (int j = 0; j < 4; ++j) {
            const int p = j * 16 + fr;
            yr[p] += d * acc[j][r];
        }
    }
}

// ---------------------------------------------------------------------------
// Fused gate + RMSNorm + pred_current + (for last rows) pred_future.
// Last-row blocks stash the normalized row in LDS and compute all 60 future
// dots themselves (4 threads x 512-elem strides + 2 shuffles) — deletes the
// separate pred_fut dispatch.
// ---------------------------------------------------------------------------
__global__ __launch_bounds__(256) void gate_norm_pred_kernel(
        const float* __restrict__ zxbcdt, const float* __restrict__ y,
        const float* __restrict__ nw, const float* __restrict__ W,
        const float* __restrict__ cur_b, const float* __restrict__ fut_b,
        float* __restrict__ out) {
    __shared__ float sY[DINNER];   // used only by last-row blocks
    const int rs = blockIdx.x;
    const int t  = threadIdx.x;
    const float* z  = zxbcdt + (size_t)rs * DINPROJ;
    const float* yr = y + (size_t)rs * DINNER;

    float vals[8];
    float ss = 0.f;
#pragma unroll
    for (int i = 0; i < 8; ++i) {
        const int c = t + i * 256;
        const float zv = z[c];
        const float v  = yr[c] * (zv / (1.f + expf(-zv)));
        vals[i] = v;
        ss += v * v;
    }
#pragma unroll
    for (int off = 32; off > 0; off >>= 1) ss += __shfl_down(ss, off, 64);
    __shared__ float red[4];
    if ((t & 63) == 0) red[t >> 6] = ss;
    __syncthreads();
    const float tot   = red[0] + red[1] + red[2] + red[3];
    const float scale = rsqrtf(tot / (float)DINNER + RMS_EPS);

    const bool is_last = ((rs & (SEQ - 1)) == SEQ - 1);
    float p0 = 0.f, p1 = 0.f, p2 = 0.f;
#pragma unroll
    for (int i = 0; i < 8; ++i) {
        const int c = t + i * 256;
        const float vn = vals[i] * scale * nw[c];
        if (is_last) sY[c] = vn;
        p0 += vn * W[c];
        p1 += vn * W[DINNER + c];
        p2 += vn * W[2 * DINNER + c];
    }
#pragma unroll
    for (int off = 32; off > 0; off >>= 1) {
        p0 += __shfl_down(p0, off, 64);
        p1 += __shfl_down(p1, off, 64);
        p2 += __shfl_down(p2, off, 64);
    }
    __shared__ float r3[4][3];
    if ((t & 63) == 0) { r3[t >> 6][0] = p0; r3[t >> 6][1] = p1; r3[t >> 6][2] = p2; }
    __syncthreads();   // also publishes sY for last-row blocks
    if (t < VNUM) {
        const float s = r3[0][t] + r3[1][t] + r3[2][t] + r3[3][t];
        out[(size_t)rs * VNUM + t] = s + cur_b[t];
    }

    if (is_last) {
        const int j = t >> 2;          // future-output index 0..59 (t<240)
        const int q = t & 3;           // 512-elem stride slice
        if (j < HORIZON * VNUM) {
            const float* wr = W + (size_t)(VNUM + j) * DINNER + q * 512;
            const float* ys = sY + q * 512;
            float pv = 0.f;
#pragma unroll 8
            for (int k = 0; k < 512; ++k) pv += ys[k] * wr[k];
            pv += __shfl_down(pv, 1, 64);
            pv += __shfl_down(pv, 2, 64);
            if (q == 0)
                out[BS * VNUM + (rs >> 9) * (HORIZON * VNUM) + j] = pv + fut_b[j];
        }
    }
}

// ---------------------------------------------------------------------------
extern "C" void kernel_launch(void* const* d_in, const int* in_sizes, int n_in,
                              void* d_out, int out_size, void* d_ws, size_t ws_size,
                              hipStream_t stream) {
    const float* embed      = (const float*)d_in[0];
    const float* in_proj_w  = (const float*)d_in[1];
    const float* conv_w     = (const float*)d_in[2];
    const float* conv_b     = (const float*)d_in[3];
    const float* dt_bias    = (const float*)d_in[4];
    const float* A_log      = (const float*)d_in[5];
    const float* Dv         = (const float*)d_in[6];
    const float* norm_w     = (const float*)d_in[7];
    const float* out_proj_w = (const float*)d_in[8];
    const float* dec_cur_w  = (const float*)d_in[9];
    const float* dec_cur_b  = (const float*)d_in[10];
    const float* dec_fut_w  = (const float*)d_in[11];
    const float* dec_fut_b  = (const float*)d_in[12];

    float* ws     = (float*)d_ws;
    float* zxbcdt = ws;                                   // BS*DINPROJ
    float* xbc    = zxbcdt + (size_t)BS * DINPROJ;        // BS*CONVDIM
    float* yraw   = xbc    + (size_t)BS * CONVDIM;        // BS*DINNER
    float* Sc     = yraw   + (size_t)BS * DINNER;         // 512*4096
    float* h0ws   = Sc     + (size_t)BATCH*NHEADS*NCHUNK*HEADDIM*DSTATE;
    float* dexp   = h0ws   + (size_t)BATCH*NHEADS*NCHUNK*HEADDIM*DSTATE;
    float* Wp     = dexp   + (size_t)BATCH*NHEADS*NCHUNK*64;  // WC_DS*64*2048
    float* W      = Wp     + (size_t)WC_DS * 64 * DINNER;     // 64*2048
    short* embB   = (short*)(W + (size_t)64 * DINNER);
    short* ipwB   = embB + (size_t)BS * DMODEL;               // NPAD1*DMODEL bf16

    float* out = (float*)d_out;

    // 0. prep: bf16 casts + decoder weight fold pass 1 (one launch)
    prep_kernel<<<CASTBLKS + 8 * WC_DS, 256, 0, stream>>>(
        embed, in_proj_w, embB, ipwB, out_proj_w, dec_cur_w, dec_fut_w, Wp);

    // 1. in-projection GEMM (bf16 MFMA): [1024,1024] x [4352,1024]^T
    gemm_bf16<128, 64, 4, 2, DMODEL>
        <<<dim3(NPAD1 / 64, BS / 128), 256, 0, stream>>>(embB, ipwB, zxbcdt, DINPROJ);

    // 2. causal conv + SiLU (coalesced, writes xbc)
    conv_kernel<<<CONVBLKS, 256, 0, stream>>>(zxbcdt, conv_w, conv_b, xbc);

    // 3. chunked SSD scan pass A (MFMA, dt-softplus inline)
    chunk_intra_kernel<<<BATCH * NHEADS * NCHUNK, 256, 0, stream>>>(
        zxbcdt, xbc, dt_bias, A_log, Dv, yraw, Sc, dexp);

    // 4. pass B (state combine, 256 blocks) + weight-fold reduce (one launch)
    comb_reduce_kernel<<<256 + 64 * DINNER / 256, 256, 0, stream>>>(
        Sc, dexp, h0ws, Wp, W);

    // 5. pass C (MFMA)
    chunk_state_out_kernel<<<BATCH * NHEADS * NCHUNK, 256, 0, stream>>>(
        xbc, h0ws, dexp, yraw);

    // 6. gate + RMSNorm + pred_current + pred_future fused (last launch)
    gate_norm_pred_kernel<<<BS, 256, 0, stream>>>(zxbcdt, yraw, norm_w, W,
                                                  dec_cur_b, dec_fut_b, out);
}

// Round 13
// 176.740 us; speedup vs baseline: 1.1483x; 1.1483x over previous
//
#include <hip/hip_runtime.h>
#include <hip/hip_bf16.h>

#define BATCH   2
#define SEQ     512
#define DMODEL  1024
#define DSTATE  64
#define HEADDIM 64
#define DCONV   4
#define VNUM    3
#define HORIZON 20
#define DINNER  2048
#define NHEADS  32
#define CONVDIM 2176   // DINNER + 2*DSTATE
#define DINPROJ 4256   // 2*DINNER + 2*DSTATE + NHEADS
#define NPAD1   4352   // DINPROJ padded to 128
#define BS      (BATCH*SEQ)   // 1024
#define RMS_EPS 1e-5f
#define CHUNK   64
#define NCHUNK  (SEQ/CHUNK)   // 8
#define NDEC    (VNUM + HORIZON*VNUM)   // 63 decoder rows
#define WC_DS   32                      // split-K slices for weight fold
#define LDB     72                      // bf16 LDS row stride (144B, 16-aligned)

typedef __attribute__((ext_vector_type(8))) short bf16x8;
typedef __attribute__((ext_vector_type(4))) float f32x4;

__device__ __forceinline__ unsigned short f2b(float x) {
    union { float f; unsigned u; } v; v.f = x;
    return (unsigned short)((v.u + 0x7fffu + ((v.u >> 16) & 1u)) >> 16);  // RNE
}

__device__ __forceinline__ float silu(float x) { return x / (1.f + expf(-x)); }

__device__ __forceinline__ void async16(const void* g, const void* l) {
    __builtin_amdgcn_global_load_lds(
        (const __attribute__((address_space(1))) unsigned int*)g,
        (__attribute__((address_space(3))) unsigned int*)l, 16, 0, 0);
}

// ---------------------------------------------------------------------------
// bf16 MFMA GEMM (NT): C[M,N]fp32 = A[M,KD]bf16 * B[Npad,KD]bf16^T.
// ---------------------------------------------------------------------------
template<int BM, int BN, int FM, int FN, int KD>
__global__ __launch_bounds__(256) void gemm_bf16(const short* __restrict__ A,
                                                 const short* __restrict__ B,
                                                 float* __restrict__ C, int N) {
    constexpr int WM = FM * 16, WN = FN * 16;
    static_assert(BM == 2 * WM && BN == 2 * WN, "2x2 waves");
    __shared__ __align__(16) short At[BM * 32];
    __shared__ __align__(16) short Bt[BN * 32];
    const int t    = threadIdx.x;
    const int lane = t & 63;
    const int w    = t >> 6;
    const int wm   = (w >> 1) * WM, wn = (w & 1) * WN;
    const int row0 = blockIdx.y * BM, col0 = blockIdx.x * BN;
    const int fr   = lane & 15;
    const int kq   = lane >> 4;
    const int lr   = t >> 2;
    const int lc   = (t & 3) * 8;

    const short* Ag = A + (size_t)(row0 + lr) * KD + lc;
    const short* Bg = B + (size_t)(col0 + lr) * KD + lc;

    f32x4 acc[FM][FN];
#pragma unroll
    for (int i = 0; i < FM; ++i)
#pragma unroll
        for (int j = 0; j < FN; ++j)
#pragma unroll
            for (int r = 0; r < 4; ++r) acc[i][j][r] = 0.f;

    for (int k0 = 0; k0 < KD; k0 += 32) {
        __syncthreads();
#pragma unroll
        for (int i = 0; i < BM / 64; ++i)
            async16(Ag + (size_t)i * 64 * KD + k0, (const char*)At + i * 4096 + t * 16);
#pragma unroll
        for (int i = 0; i < BN / 64; ++i)
            async16(Bg + (size_t)i * 64 * KD + k0, (const char*)Bt + i * 4096 + t * 16);
        __syncthreads();

        bf16x8 af[FM], bv[FN];
#pragma unroll
        for (int i = 0; i < FM; ++i)
            af[i] = *(const bf16x8*)&At[(wm + i * 16 + fr) * 32 + kq * 8];
#pragma unroll
        for (int j = 0; j < FN; ++j)
            bv[j] = *(const bf16x8*)&Bt[(wn + j * 16 + fr) * 32 + kq * 8];
#pragma unroll
        for (int i = 0; i < FM; ++i)
#pragma unroll
            for (int j = 0; j < FN; ++j)
                acc[i][j] = __builtin_amdgcn_mfma_f32_16x16x32_bf16(
                    af[i], bv[j], acc[i][j], 0, 0, 0);
    }

    const int orow = lane >> 4;
#pragma unroll
    for (int i = 0; i < FM; ++i)
#pragma unroll
        for (int j = 0; j < FN; ++j) {
            const int col = col0 + wn + j * 16 + fr;
            if (col < N) {
#pragma unroll
                for (int r = 0; r < 4; ++r) {
                    const int row = row0 + wm + i * 16 + orow * 4 + r;
                    C[(size_t)row * N + col] = acc[i][j][r];
                }
            }
        }
}

// ---------------------------------------------------------------------------
// prep: fused fp32->bf16 casts (embed + padded in_proj_w) AND decoder weight
// fold pass 1.  P[ds][v][i] = sum_{d in 32-slice} decw[v][d] * op[d][i]
// ---------------------------------------------------------------------------
#define EMB4     (BS * DMODEL / 4)          // 262144
#define IPW4     (NPAD1 * DMODEL / 4)       // 1114112
#define CASTBLKS ((EMB4 + IPW4) / 256)      // 5376
__global__ __launch_bounds__(256) void prep_kernel(
        const float* __restrict__ embed, const float* __restrict__ ipw,
        short* __restrict__ embB, short* __restrict__ ipwB,
        const float* __restrict__ op, const float* __restrict__ cwv,
        const float* __restrict__ fwv, float* __restrict__ P) {
    __shared__ float lw[32][64];   // [d][v], v padded to 64 with zeros
    if (blockIdx.x < CASTBLKS) {
        const int i = blockIdx.x * 256 + threadIdx.x;
        if (i < EMB4) {
            float4 v = *(const float4*)(embed + (size_t)i * 4);
            *(short4*)(embB + (size_t)i * 4) =
                make_short4((short)f2b(v.x), (short)f2b(v.y),
                            (short)f2b(v.z), (short)f2b(v.w));
        } else {
            const int j = i - EMB4;
            const size_t e0 = (size_t)j * 4;
            const int row = (int)(e0 / DMODEL);
            short4 o;
            if (row < DINPROJ) {
                float4 v = *(const float4*)(ipw + e0);
                o = make_short4((short)f2b(v.x), (short)f2b(v.y),
                                (short)f2b(v.z), (short)f2b(v.w));
            } else {
                o = make_short4(0, 0, 0, 0);
            }
            *(short4*)(ipwB + e0) = o;
        }
        return;
    }
    const int blk   = blockIdx.x - CASTBLKS;   // 0..255
    const int itile = blk & 7;
    const int ds    = blk >> 3;
    const int i     = itile * 256 + threadIdx.x;
    const int d0    = ds * 32;

#pragma unroll
    for (int k = 0; k < 8; ++k) {
        const int e = threadIdx.x * 8 + k;    // 0..2047
        const int d = e >> 6, v = e & 63;
        float val = 0.f;
        if (v < VNUM)      val = cwv[(size_t)v * DMODEL + d0 + d];
        else if (v < NDEC) val = fwv[(size_t)(v - VNUM) * DMODEL + d0 + d];
        lw[d][v] = val;
    }

    float opc[32];
#pragma unroll
    for (int d = 0; d < 32; ++d) opc[d] = op[(size_t)(d0 + d) * DINNER + i];
    __syncthreads();

    f32x4 acc[16];
#pragma unroll
    for (int q = 0; q < 16; ++q)
#pragma unroll
        for (int r = 0; r < 4; ++r) acc[q][r] = 0.f;

#pragma unroll
    for (int d = 0; d < 32; ++d) {
        const float o = opc[d];
#pragma unroll
        for (int q = 0; q < 16; ++q) {
            float4 wv = *(const float4*)&lw[d][q * 4];
            acc[q][0] += o * wv.x; acc[q][1] += o * wv.y;
            acc[q][2] += o * wv.z; acc[q][3] += o * wv.w;
        }
    }

    float* Pp = P + (size_t)ds * 64 * DINNER + i;
#pragma unroll
    for (int q = 0; q < 16; ++q)
#pragma unroll
        for (int r = 0; r < 4; ++r)
            Pp[(size_t)(q * 4 + r) * DINNER] = acc[q][r];
}

// ---------------------------------------------------------------------------
// Causal conv1d(4)+bias+SiLU over the xBC slice, vectorized x4, coalesced.
// ---------------------------------------------------------------------------
#define CONVBLKS (BS * CONVDIM / 4 / 256)   // 2176
__global__ __launch_bounds__(256) void conv_kernel(
        const float* __restrict__ zxbcdt, const float* __restrict__ cw,
        const float* __restrict__ cb, float* __restrict__ xbc) {
    const int item = blockIdx.x * 256 + threadIdx.x;
    const int c4 = item % (CONVDIM / 4);
    const int rs = item / (CONVDIM / 4);
    const int s  = rs % SEQ;
    const int c  = c4 * 4;
    const float* src = zxbcdt + (size_t)rs * DINPROJ + DINNER + c;
    float4 x0 = (s >= 3) ? *(const float4*)(src - 3 * DINPROJ) : make_float4(0,0,0,0);
    float4 x1 = (s >= 2) ? *(const float4*)(src - 2 * DINPROJ) : make_float4(0,0,0,0);
    float4 x2 = (s >= 1) ? *(const float4*)(src - 1 * DINPROJ) : make_float4(0,0,0,0);
    float4 x3 = *(const float4*)(src);
    float4 bias = *(const float4*)(cb + c);
    float4 r;
    { float4 w = *(const float4*)(cw + (size_t)(c+0)*4);
      r.x = bias.x + w.x*x0.x + w.y*x1.x + w.z*x2.x + w.w*x3.x; }
    { float4 w = *(const float4*)(cw + (size_t)(c+1)*4);
      r.y = bias.y + w.x*x0.y + w.y*x1.y + w.z*x2.y + w.w*x3.y; }
    { float4 w = *(const float4*)(cw + (size_t)(c+2)*4);
      r.z = bias.z + w.x*x0.z + w.y*x1.z + w.z*x2.z + w.w*x3.z; }
    { float4 w = *(const float4*)(cw + (size_t)(c+3)*4);
      r.w = bias.w + w.x*x0.w + w.y*x1.w + w.z*x2.w + w.w*x3.w; }
    r.x = silu(r.x); r.y = silu(r.y); r.z = silu(r.z); r.w = silu(r.w);
    *(float4*)(xbc + (size_t)rs * CONVDIM + c) = r;
}

// ---------------------------------------------------------------------------
// Chunked SSD scan, pass A — MFMA. Three 64x64x64 contractions per block:
//   GEMM1: Mraw[t][s] = sum_n C[t][n] B[s][n]  -> mask/exp -> sM (bf16)
//   GEMM2: Y[t][p]    = sum_s M[t][s] Ut[p][s] (+ D*x, exact fp32 x)
//   GEMM3: Sc[p][n]   = sum_s Ue[p][s] Bn[n][s]   (Ue = U * se[s])
// ---------------------------------------------------------------------------
__global__ __launch_bounds__(256) void chunk_intra_kernel(
        const float* __restrict__ zx, const float* __restrict__ xbc,
        const float* __restrict__ dt_bias, const float* __restrict__ A_log,
        const float* __restrict__ Dv, float* __restrict__ yraw,
        float* __restrict__ Sc, float* __restrict__ dexp) {
    const int blk = blockIdx.x;      // ((b*32+h)*8 + c)
    const int c  = blk & 7;
    const int bh = blk >> 3;
    const int h  = bh & 31;
    const int b  = bh >> 5;
    const int rs0 = b * SEQ + c * CHUNK;

    __shared__ __align__(16) short sB [64 * LDB];  // [s][n]
    __shared__ __align__(16) short sCt[64 * LDB];  // [t][n]
    __shared__ __align__(16) short sBn[64 * LDB];  // [n][s]
    __shared__ __align__(16) short sUt[64 * LDB];  // [p][s]
    __shared__ __align__(16) short sUe[64 * LDB];  // [p][s] * se[s]
    __shared__ __align__(16) short sM [64 * LDB];  // [t][s]
    __shared__ float sl[64], se[64], sdt[64];

    const int tid  = threadIdx.x;
    const int lane = tid & 63;
    const int w    = tid >> 6;
    const int fr   = lane & 15;
    const int kq   = lane >> 4;
    const int wm   = w * 16;       // wave's 16-row output strip
    const float A  = -expf(A_log[h]);

    // ---- stage B[s][n], C[t][n] (row-major) and Bn[n][s] (transposed) ----
    {
        const int row = tid >> 2;
        const int cq  = tid & 3;
        const float* xrow = xbc + (size_t)(rs0 + row) * CONVDIM + DINNER;
#pragma unroll
        for (int i = 0; i < 4; ++i) {
            const int n = cq * 16 + i * 4;
            float4 bv = *(const float4*)(xrow + n);
            float4 cv = *(const float4*)(xrow + DSTATE + n);
            short4 bs = make_short4((short)f2b(bv.x), (short)f2b(bv.y),
                                    (short)f2b(bv.z), (short)f2b(bv.w));
            short4 cs = make_short4((short)f2b(cv.x), (short)f2b(cv.y),
                                    (short)f2b(cv.z), (short)f2b(cv.w));
            *(short4*)&sB [row * LDB + n] = bs;
            *(short4*)&sCt[row * LDB + n] = cs;
            sBn[(n+0) * LDB + row] = bs.x;
            sBn[(n+1) * LDB + row] = bs.y;
            sBn[(n+2) * LDB + row] = bs.z;
            sBn[(n+3) * LDB + row] = bs.w;
        }
    }

    // ---- dt = softplus(raw + bias); cumsum(dt*A) (wave 0) ----
    if (tid < 64) {
        const float raw = zx[(size_t)(rs0 + tid) * DINPROJ + DINNER + CONVDIM + h]
                          + dt_bias[h];
        const float dtv = fmaxf(raw, 0.f) + log1pf(expf(-fabsf(raw)));
        sdt[tid] = dtv;
        float v = dtv * A;
#pragma unroll
        for (int off = 1; off < 64; off <<= 1) {
            float o = __shfl_up(v, off, 64);
            if (tid >= off) v += o;
        }
        sl[tid] = v;
        const float ltot = __shfl(v, 63, 64);
        se[tid] = expf(ltot - v);
        dexp[(size_t)blk * 64 + tid] = expf(v);
    }
    __syncthreads();

    // ---- GEMM1: Mraw (strip t in [wm, wm+16)) ----
    f32x4 accM[4];
#pragma unroll
    for (int j = 0; j < 4; ++j)
#pragma unroll
        for (int r = 0; r < 4; ++r) accM[j][r] = 0.f;
#pragma unroll
    for (int k0 = 0; k0 < 64; k0 += 32) {
        bf16x8 af = *(const bf16x8*)&sCt[(wm + fr) * LDB + kq * 8 + k0];
#pragma unroll
        for (int j = 0; j < 4; ++j) {
            bf16x8 bv = *(const bf16x8*)&sB[(j * 16 + fr) * LDB + kq * 8 + k0];
            accM[j] = __builtin_amdgcn_mfma_f32_16x16x32_bf16(af, bv, accM[j], 0, 0, 0);
        }
    }
    // mask + exp, write M[t][s] bf16
    {
        const int t0 = wm + kq * 4;
        const float lt0 = sl[t0+0], lt1 = sl[t0+1], lt2 = sl[t0+2], lt3 = sl[t0+3];
#pragma unroll
        for (int j = 0; j < 4; ++j) {
            const int s = j * 16 + fr;
            const float ls = sl[s];
            sM[(t0+0)*LDB + s] = (short)f2b((s <= t0+0) ? expf(lt0-ls)*accM[j][0] : 0.f);
            sM[(t0+1)*LDB + s] = (short)f2b((s <= t0+1) ? expf(lt1-ls)*accM[j][1] : 0.f);
            sM[(t0+2)*LDB + s] = (short)f2b((s <= t0+2) ? expf(lt2-ls)*accM[j][2] : 0.f);
            sM[(t0+3)*LDB + s] = (short)f2b((s <= t0+3) ? expf(lt3-ls)*accM[j][3] : 0.f);
        }
    }

    // ---- stage Ut[p][s] = dt_s*x[s][p] and Ue = Ut*se[s] ----
    {
        const int row = tid >> 2;     // s
        const int cq  = tid & 3;
        const float dtv = sdt[row];
        const float sev = se[row];
        const float* xr = xbc + (size_t)(rs0 + row) * CONVDIM + h * HEADDIM;
#pragma unroll
        for (int i = 0; i < 4; ++i) {
            const int p = cq * 16 + i * 4;
            float4 xv = *(const float4*)(xr + p);
            const float u0 = dtv * xv.x, u1 = dtv * xv.y;
            const float u2 = dtv * xv.z, u3 = dtv * xv.w;
            sUt[(p+0)*LDB + row] = (short)f2b(u0);
            sUt[(p+1)*LDB + row] = (short)f2b(u1);
            sUt[(p+2)*LDB + row] = (short)f2b(u2);
            sUt[(p+3)*LDB + row] = (short)f2b(u3);
            sUe[(p+0)*LDB + row] = (short)f2b(u0 * sev);
            sUe[(p+1)*LDB + row] = (short)f2b(u1 * sev);
            sUe[(p+2)*LDB + row] = (short)f2b(u2 * sev);
            sUe[(p+3)*LDB + row] = (short)f2b(u3 * sev);
        }
    }
    __syncthreads();

    // ---- GEMM2: Y (strip t = wm) ----
    f32x4 accY[4];
#pragma unroll
    for (int j = 0; j < 4; ++j)
#pragma unroll
        for (int r = 0; r < 4; ++r) accY[j][r] = 0.f;
#pragma unroll
    for (int k0 = 0; k0 < 64; k0 += 32) {
        bf16x8 af = *(const bf16x8*)&sM[(wm + fr) * LDB + kq * 8 + k0];
#pragma unroll
        for (int j = 0; j < 4; ++j) {
            bf16x8 bv = *(const bf16x8*)&sUt[(j * 16 + fr) * LDB + kq * 8 + k0];
            accY[j] = __builtin_amdgcn_mfma_f32_16x16x32_bf16(af, bv, accY[j], 0, 0, 0);
        }
    }
    // ---- GEMM3: Sc (strip p = wm) ----
    f32x4 accS[4];
#pragma unroll
    for (int j = 0; j < 4; ++j)
#pragma unroll
        for (int r = 0; r < 4; ++r) accS[j][r] = 0.f;
#pragma unroll
    for (int k0 = 0; k0 < 64; k0 += 32) {
        bf16x8 af = *(const bf16x8*)&sUe[(wm + fr) * LDB + kq * 8 + k0];
#pragma unroll
        for (int j = 0; j < 4; ++j) {
            bf16x8 bv = *(const bf16x8*)&sBn[(j * 16 + fr) * LDB + kq * 8 + k0];
            accS[j] = __builtin_amdgcn_mfma_f32_16x16x32_bf16(af, bv, accS[j], 0, 0, 0);
        }
    }

    // ---- Y epilogue (+ D*x, exact fp32 x) ----
    {
        const float Dh = Dv[h];
        const int t0 = wm + kq * 4;
#pragma unroll
        for (int r = 0; r < 4; ++r) {
            const int t = t0 + r;
            const float* xr = xbc + (size_t)(rs0 + t) * CONVDIM + h * HEADDIM;
            float* yr = yraw + (size_t)(rs0 + t) * DINNER + h * HEADDIM;
#pragma unroll
            for (int j = 0; j < 4; ++j) {
                const int p = j * 16 + fr;
                yr[p] = accY[j][r] + Dh * xr[p];
            }
        }
    }
    // ---- Sc epilogue ----
    {
        float* scp = Sc + (size_t)blk * (HEADDIM * DSTATE);
        const int p0 = wm + kq * 4;
#pragma unroll
        for (int r = 0; r < 4; ++r)
#pragma unroll
            for (int j = 0; j < 4; ++j)
                scp[(size_t)(p0 + r) * DSTATE + j * 16 + fr] = accS[j][r];
    }
}

// ---------------------------------------------------------------------------
// Fused pass B (inter-chunk state combine, 4 blocks per (b,h))
// + decoder weight fold pass 2.
// ---------------------------------------------------------------------------
__global__ __launch_bounds__(256) void comb_reduce_kernel(
        const float* __restrict__ Sc, const float* __restrict__ dexp,
        float* __restrict__ h0ws, const float* __restrict__ P,
        float* __restrict__ W) {
    if (blockIdx.x < 256) {
        const int bh = blockIdx.x >> 2;
        const int e  = (blockIdx.x & 3) * 1024 + threadIdx.x * 4;
        float4 h = make_float4(0.f, 0.f, 0.f, 0.f);
        for (int c = 0; c < NCHUNK; ++c) {
            const size_t base = (size_t)(bh * NCHUNK + c) * (HEADDIM * DSTATE);
            const float ac = dexp[(size_t)(bh * NCHUNK + c) * 64 + 63];
            *(float4*)&h0ws[base + e] = h;
            float4 s = *(const float4*)&Sc[base + e];
            h.x = ac * h.x + s.x; h.y = ac * h.y + s.y;
            h.z = ac * h.z + s.z; h.w = ac * h.w + s.w;
        }
    } else {
        const int idx = (blockIdx.x - 256) * 256 + threadIdx.x;   // < 64*DINNER
        float s = 0.f;
#pragma unroll
        for (int ds = 0; ds < WC_DS; ++ds) s += P[(size_t)ds * 64 * DINNER + idx];
        W[idx] = s;
    }
}

// ---------------------------------------------------------------------------
// Pass C — MFMA: Yst[t][p] = dexp[t] * sum_n C[t][n] h0[p][n].
// ---------------------------------------------------------------------------
__global__ __launch_bounds__(256) void chunk_state_out_kernel(
        const float* __restrict__ xbc, const float* __restrict__ h0ws,
        const float* __restrict__ dexp, float* __restrict__ yraw) {
    const int blk = blockIdx.x;
    const int c  = blk & 7;
    if (c == 0) return;
    const int bh = blk >> 3;
    const int h  = bh & 31;
    const int b  = bh >> 5;
    const int rs0 = b * SEQ + c * CHUNK;

    __shared__ __align__(16) short sCt[64 * LDB];  // [t][n]
    __shared__ __align__(16) short sH [64 * LDB];  // [p][n]
    __shared__ float sdex[64];

    const int tid  = threadIdx.x;
    const int lane = tid & 63;
    const int w    = tid >> 6;
    const int fr   = lane & 15;
    const int kq   = lane >> 4;
    const int wm   = w * 16;
    {
        const int row = tid >> 2;
        const int cq  = tid & 3;
        const float* xrow = xbc + (size_t)(rs0 + row) * CONVDIM + DINNER + DSTATE;
        const float* hrow = h0ws + (size_t)blk * (HEADDIM * DSTATE)
                            + (size_t)row * DSTATE;
#pragma unroll
        for (int i = 0; i < 4; ++i) {
            const int n = cq * 16 + i * 4;
            float4 cv = *(const float4*)(xrow + n);
            float4 hv = *(const float4*)(hrow + n);
            *(short4*)&sCt[row * LDB + n] =
                make_short4((short)f2b(cv.x), (short)f2b(cv.y),
                            (short)f2b(cv.z), (short)f2b(cv.w));
            *(short4*)&sH[row * LDB + n] =
                make_short4((short)f2b(hv.x), (short)f2b(hv.y),
                            (short)f2b(hv.z), (short)f2b(hv.w));
        }
    }
    if (tid < 64) sdex[tid] = dexp[(size_t)blk * 64 + tid];
    __syncthreads();

    f32x4 acc[4];
#pragma unroll
    for (int j = 0; j < 4; ++j)
#pragma unroll
        for (int r = 0; r < 4; ++r) acc[j][r] = 0.f;
#pragma unroll
    for (int k0 = 0; k0 < 64; k0 += 32) {
        bf16x8 af = *(const bf16x8*)&sCt[(wm + fr) * LDB + kq * 8 + k0];
#pragma unroll
        for (int j = 0; j < 4; ++j) {
            bf16x8 bv = *(const bf16x8*)&sH[(j * 16 + fr) * LDB + kq * 8 + k0];
            acc[j] = __builtin_amdgcn_mfma_f32_16x16x32_bf16(af, bv, acc[j], 0, 0, 0);
        }
    }
    const int t0 = wm + kq * 4;
#pragma unroll
    for (int r = 0; r < 4; ++r) {
        const int t = t0 + r;
        const float d = sdex[t];
        float* yr = yraw + (size_t)(rs0 + t) * DINNER + h * HEADDIM;
#pragma unroll
        for (int j = 0; j < 4; ++j) {
            const int p = j * 16 + fr;
            yr[p] += d * acc[j][r];
        }
    }
}

// ---------------------------------------------------------------------------
// Fused gate + RMSNorm + pred_current + last-row stash.
// ---------------------------------------------------------------------------
__global__ __launch_bounds__(256) void gate_norm_pred_kernel(
        const float* __restrict__ zxbcdt, const float* __restrict__ y,
        const float* __restrict__ nw, const float* __restrict__ W,
        const float* __restrict__ cur_b, float* __restrict__ out,
        float* __restrict__ ylast) {
    const int rs = blockIdx.x;
    const int t  = threadIdx.x;
    const float* z  = zxbcdt + (size_t)rs * DINPROJ;
    const float* yr = y + (size_t)rs * DINNER;

    float vals[8];
    float ss = 0.f;
#pragma unroll
    for (int i = 0; i < 8; ++i) {
        const int c = t + i * 256;
        const float zv = z[c];
        const float v  = yr[c] * (zv / (1.f + expf(-zv)));
        vals[i] = v;
        ss += v * v;
    }
#pragma unroll
    for (int off = 32; off > 0; off >>= 1) ss += __shfl_down(ss, off, 64);
    __shared__ float red[4];
    if ((t & 63) == 0) red[t >> 6] = ss;
    __syncthreads();
    const float tot   = red[0] + red[1] + red[2] + red[3];
    const float scale = rsqrtf(tot / (float)DINNER + RMS_EPS);

    const bool is_last = ((rs & (SEQ - 1)) == SEQ - 1);
    float p0 = 0.f, p1 = 0.f, p2 = 0.f;
#pragma unroll
    for (int i = 0; i < 8; ++i) {
        const int c = t + i * 256;
        const float vn = vals[i] * scale * nw[c];
        vals[i] = vn;
        p0 += vn * W[c];
        p1 += vn * W[DINNER + c];
        p2 += vn * W[2 * DINNER + c];
    }
    if (is_last) {
        float* yl = ylast + (size_t)(rs >> 9) * DINNER;
#pragma unroll
        for (int i = 0; i < 8; ++i) yl[t + i * 256] = vals[i];
    }
#pragma unroll
    for (int off = 32; off > 0; off >>= 1) {
        p0 += __shfl_down(p0, off, 64);
        p1 += __shfl_down(p1, off, 64);
        p2 += __shfl_down(p2, off, 64);
    }
    __shared__ float r3[4][3];
    if ((t & 63) == 0) { r3[t >> 6][0] = p0; r3[t >> 6][1] = p1; r3[t >> 6][2] = p2; }
    __syncthreads();
    if (t < VNUM) {
        const float s = r3[0][t] + r3[1][t] + r3[2][t] + r3[3][t];
        out[(size_t)rs * VNUM + t] = s + cur_b[t];
    }
}

// ---------------------------------------------------------------------------
// pred_future: block per (b, j); dot(ylast[b], W[VNUM+j]) + fut_b[j].
// ---------------------------------------------------------------------------
__global__ __launch_bounds__(256) void pred_fut_kernel(
        const float* __restrict__ ylast, const float* __restrict__ W,
        const float* __restrict__ bvec, float* __restrict__ out) {
    const int blk = blockIdx.x;
    const int b = blk / (HORIZON * VNUM);
    const int j = blk % (HORIZON * VNUM);
    const float* yl = ylast + (size_t)b * DINNER;
    const float* wr = W + (size_t)(VNUM + j) * DINNER;
    float pv = 0.f;
    for (int i = threadIdx.x; i < DINNER; i += 256) pv += yl[i] * wr[i];
#pragma unroll
    for (int off = 32; off > 0; off >>= 1) pv += __shfl_down(pv, off, 64);
    __shared__ float red[4];
    if ((threadIdx.x & 63) == 0) red[threadIdx.x >> 6] = pv;
    __syncthreads();
    if (threadIdx.x == 0)
        out[b * (HORIZON * VNUM) + j] = red[0] + red[1] + red[2] + red[3] + bvec[j];
}

// ---------------------------------------------------------------------------
extern "C" void kernel_launch(void* const* d_in, const int* in_sizes, int n_in,
                              void* d_out, int out_size, void* d_ws, size_t ws_size,
                              hipStream_t stream) {
    const float* embed      = (const float*)d_in[0];
    const float* in_proj_w  = (const float*)d_in[1];
    const float* conv_w     = (const float*)d_in[2];
    const float* conv_b     = (const float*)d_in[3];
    const float* dt_bias    = (const float*)d_in[4];
    const float* A_log      = (const float*)d_in[5];
    const float* Dv         = (const float*)d_in[6];
    const float* norm_w     = (const float*)d_in[7];
    const float* out_proj_w = (const float*)d_in[8];
    const float* dec_cur_w  = (const float*)d_in[9];
    const float* dec_cur_b  = (const float*)d_in[10];
    const float* dec_fut_w  = (const float*)d_in[11];
    const float* dec_fut_b  = (const float*)d_in[12];

    float* ws     = (float*)d_ws;
    float* zxbcdt = ws;                                   // BS*DINPROJ
    float* xbc    = zxbcdt + (size_t)BS * DINPROJ;        // BS*CONVDIM
    float* yraw   = xbc    + (size_t)BS * CONVDIM;        // BS*DINNER
    float* Sc     = yraw   + (size_t)BS * DINNER;         // 512*4096
    float* h0ws   = Sc     + (size_t)BATCH*NHEADS*NCHUNK*HEADDIM*DSTATE;
    float* dexp   = h0ws   + (size_t)BATCH*NHEADS*NCHUNK*HEADDIM*DSTATE;
    float* Wp     = dexp   + (size_t)BATCH*NHEADS*NCHUNK*64;  // WC_DS*64*2048
    float* W      = Wp     + (size_t)WC_DS * 64 * DINNER;     // 64*2048
    float* ylast  = W      + (size_t)64 * DINNER;             // 2*2048
    short* embB   = (short*)(ylast + (size_t)BATCH * DINNER);
    short* ipwB   = embB + (size_t)BS * DMODEL;               // NPAD1*DMODEL bf16

    float* out = (float*)d_out;

    // 0. prep: bf16 casts + decoder weight fold pass 1 (one launch)
    prep_kernel<<<CASTBLKS + 8 * WC_DS, 256, 0, stream>>>(
        embed, in_proj_w, embB, ipwB, out_proj_w, dec_cur_w, dec_fut_w, Wp);

    // 1. in-projection GEMM (bf16 MFMA): [1024,1024] x [4352,1024]^T
    gemm_bf16<128, 64, 4, 2, DMODEL>
        <<<dim3(NPAD1 / 64, BS / 128), 256, 0, stream>>>(embB, ipwB, zxbcdt, DINPROJ);

    // 2. causal conv + SiLU (coalesced, writes xbc)
    conv_kernel<<<CONVBLKS, 256, 0, stream>>>(zxbcdt, conv_w, conv_b, xbc);

    // 3. chunked SSD scan pass A (MFMA, dt-softplus inline)
    chunk_intra_kernel<<<BATCH * NHEADS * NCHUNK, 256, 0, stream>>>(
        zxbcdt, xbc, dt_bias, A_log, Dv, yraw, Sc, dexp);

    // 4. pass B (state combine, 256 blocks) + weight-fold reduce (one launch)
    comb_reduce_kernel<<<256 + 64 * DINNER / 256, 256, 0, stream>>>(
        Sc, dexp, h0ws, Wp, W);

    // 5. pass C (MFMA)
    chunk_state_out_kernel<<<BATCH * NHEADS * NCHUNK, 256, 0, stream>>>(
        xbc, h0ws, dexp, yraw);

    // 6. gate + RMSNorm + pred_current fused
    gate_norm_pred_kernel<<<BS, 256, 0, stream>>>(zxbcdt, yraw, norm_w, W,
                                                  dec_cur_b, out, ylast);

    // 7. pred_future from stashed last rows
    pred_fut_kernel<<<BATCH * HORIZON * VNUM, 256, 0, stream>>>(ylast, W, dec_fut_b,
                                                                out + BS * VNUM);
}